// Round 7
// baseline (793.474 us; speedup 1.0000x reference)
//
#include <hip/hip_runtime.h>

// Problem constants
#define COLS_ 1453
#define NC 132
#define EGS 1792       // E row stride: [g-map 0..1535 | u-map 1536..1663 | y-map 1664..1791]
#define NB 8192

// f64 scratch offsets (doubles) in d_out g-region (dead before gemm1 writes g).
// W rows: 0..63 Up(ud), 64..191 Uf(ud), 192..255 Yp(yd), 256..383 Yf(yd).
#define oGam 0          // Gamma 384x384
#define oC   147456     // c    384x128
#define oV   196608     // v    132x128
#define oGC  213504     // Gamma*c 384x128
#define oCK  262656     // cK   384x128
#define oVK  311808     // vK   132x128
#define oGCK 328704     // Gamma*cK 384x128
#define oB   377856     // [B|I] 128x256
#define oP   410624     // (unused)
#define oR   414980     // (unused)
#define oJ   431364     // 128x256
#define oF   464132     // 128x256
#define oCE  496900     // CEt 256x384 (transposed)   (end 595204 dbl = 4.76 MB)
// Eh/El (bf16 256x1792 each = 1.79 MB total) live in d_ws (same footprint as the
// old f32 Egt, R4-proven region).

typedef short v8s __attribute__((ext_vector_type(8)));    // 8 bf16 (4 VGPRs)
typedef float v4f __attribute__((ext_vector_type(4)));    // MFMA acc

__device__ __forceinline__ double hash01(unsigned i, unsigned j) {
  unsigned x = i * 0x9E3779B9u ^ (j * 0x85EBCA6Bu + 0xC2B2AE35u);
  x ^= x >> 16; x *= 0x7FEB352Du; x ^= x >> 15; x *= 0x846CA68Bu; x ^= x >> 16;
  return (double)(x & 0xFFFFFF) / 8388608.0 - 1.0;
}

// bf16 helpers (RNE)
__device__ __forceinline__ unsigned short f2bf(float x) {
  union { float f; unsigned u; } v; v.f = x;
  unsigned r = (v.u + 0x7FFFu + ((v.u >> 16) & 1u)) >> 16;
  return (unsigned short)r;
}
__device__ __forceinline__ float bf2f(unsigned short h) {
  union { unsigned u; float f; } v; v.u = ((unsigned)h) << 16; return v.f;
}

// ---------------- Gram: Gamma = W W^T  (R2-proven structure, +ILP) ----------------
__global__ void k_gram(const float* __restrict__ ud, const float* __restrict__ yd,
                       double* __restrict__ G) {
  __shared__ float sig[12000];
  int tid = threadIdx.y * 16 + threadIdx.x;
  for (int idx = tid; idx < 6000; idx += 256) { sig[idx] = ud[idx]; sig[6000 + idx] = yd[idx]; }
  __syncthreads();
  int i = blockIdx.y * 16 + threadIdx.y;
  int j = blockIdx.x * 16 + threadIdx.x;
  const float* si = &sig[(i < 192) ? i : (6000 + i - 192)];
  const float* sj = &sig[(j < 192) ? j : (6000 + j - 192)];
  double a0 = 0.0, a1 = 0.0, a2 = 0.0, a3 = 0.0;
  for (int c = 0; c < 1452; c += 4) {
    a0 += (double)si[4 * c]      * (double)sj[4 * c];
    a1 += (double)si[4 * c + 4]  * (double)sj[4 * c + 4];
    a2 += (double)si[4 * c + 8]  * (double)sj[4 * c + 8];
    a3 += (double)si[4 * c + 12] * (double)sj[4 * c + 12];
  }
  a0 += (double)si[4 * 1452] * (double)sj[4 * 1452];
  G[i * 384 + j] = (a0 + a1) + (a2 + a3);
}

// ---------------- init c (384x128) and v (132x128) ----------------
__global__ void k_initc(double* __restrict__ c, double* __restrict__ v) {
  int z = blockIdx.x * 16 + threadIdx.x;
  int i = blockIdx.y * 16 + threadIdx.y;
  if (i < 384) c[i * 128 + z] = hash01(i, z);
  else if (i < 516) v[(i - 384) * 128 + z] = hash01(i + 1000, z);
}

// ---------------- GC = Gamma @ c  (384x128) ----------------
__global__ void k_G(const double* __restrict__ Gam, const double* __restrict__ c,
                    double* __restrict__ outp) {
  int z = blockIdx.x * 16 + threadIdx.x;
  int i = blockIdx.y * 16 + threadIdx.y;
  double a0 = 0.0, a1 = 0.0;
  for (int t = 0; t < 384; t += 2) {
    a0 += Gam[i * 384 + t]     * c[t * 128 + z];
    a1 += Gam[i * 384 + t + 1] * c[(t + 1) * 128 + z];
  }
  outp[i * 128 + z] = a0 + a1;
}

// ---------------- K-apply in coordinates: (GC, v) -> (cK, vK) ----------------
__global__ void k_step(const double* __restrict__ GC, const double* __restrict__ v,
                       const float* __restrict__ q, const float* __restrict__ r,
                       double* __restrict__ cK, double* __restrict__ vK) {
  int z = blockIdx.x * 16 + threadIdx.x;
  int i = blockIdx.y * 16 + threadIdx.y;
  if (i >= 516) return;
  if (i < 384) {
    double val;
    if (i < 64)        val = v[i * 128 + z];                                   // A^T v, Up rows
    else if (i < 192)  { int m = i - 64;  val = 2.0 * (double)r[m & 3] * GC[i * 128 + z]; }
    else if (i < 256)  val = v[(64 + i - 192) * 128 + z];                      // A^T v, Yp rows
    else {
      int m = i - 256;
      val = 2.0 * (double)q[m & 3] * GC[i * 128 + z];
      if (m >= 124) val += v[(128 + m - 124) * 128 + z];                        // terminal rows
    }
    cK[i * 128 + z] = val;
  } else {
    int rr = i - 384;
    double val;
    if (rr < 64)       val = GC[rr * 128 + z];                                 // Up g
    else if (rr < 128) val = GC[(192 + rr - 64) * 128 + z];                    // Yp g
    else               val = GC[(380 + rr - 128) * 128 + z];                   // Yf last 4
    vK[rr * 128 + z] = val;
  }
}

// ---------------- normalize columns: scale c, v, GC by 1/||z|| ----------------
__global__ void k_normc(double* __restrict__ c, double* __restrict__ v, double* __restrict__ GC) {
  __shared__ double red[256];
  int z = blockIdx.x, tid = threadIdx.x;
  double s = 0.0;
  for (int i = tid; i < 384; i += 256) s += c[i * 128 + z] * GC[i * 128 + z];
  for (int rr = tid; rr < 132; rr += 256) { double t = v[rr * 128 + z]; s += t * t; }
  red[tid] = s; __syncthreads();
  for (int st = 128; st > 0; st >>= 1) { if (tid < st) red[tid] += red[tid + st]; __syncthreads(); }
  double inv = rsqrt(red[0]);
  for (int i = tid; i < 384; i += 256) { c[i * 128 + z] *= inv; GC[i * 128 + z] *= inv; }
  for (int rr = tid; rr < 132; rr += 256) v[rr * 128 + z] *= inv;
}

// ---------------- Baug = [ c^T GCK + v^T vK | I ]  (128x256) ----------------
__global__ void k_B(const double* __restrict__ c, const double* __restrict__ GCK,
                    const double* __restrict__ v, const double* __restrict__ vK,
                    double* __restrict__ Baug) {
  int z2 = blockIdx.x * 16 + threadIdx.x;
  int z1 = blockIdx.y * 16 + threadIdx.y;
  if (z2 >= 128) { Baug[z1 * 256 + z2] = ((z2 - 128) == z1) ? 1.0 : 0.0; return; }
  double a0 = 0.0, a1 = 0.0;
  for (int i = 0; i < 384; i += 2) {
    a0 += c[i * 128 + z1] * GCK[i * 128 + z2];
    a1 += c[(i + 1) * 128 + z1] * GCK[(i + 1) * 128 + z2];
  }
  for (int rr = 0; rr < 132; ++rr) a0 += v[rr * 128 + z1] * vK[rr * 128 + z2];
  Baug[z1 * 256 + z2] = a0 + a1;
}

// ---------------- single-workgroup 128x128 in-place GJ inverse (512 threads) ----------------
// Thread (r, cg) owns 32 CONTIGUOUS cols [cg*32, cg*32+32) of row r in registers
// (static indexing; contiguous -> pivot-row reads merge to ds_read_b128 with 16-lane
// broadcast, conflict-free). Same fused multiplier recipe as the HW-proven k_inv64:
//   fp = (r==k) ? (1-pv) : fik*pv;  a[j] -= fp * pr[j]  (row k: pv*A[k][j])
//   col k afterwards: a = isk ? pv : -fik*pv
// Double-buffered pivot staging (parity k&1) -> ONE barrier per step; 128 steps.
// Same pivot order (0..127, unpivoted) as the previous blocked 2x64 version.
// Writes the inverse into Baug cols 128..255 (what k_F reads).
__global__ __launch_bounds__(512) void k_inv128(double* __restrict__ Ba) {
  __shared__ double pr[2][128];   // unscaled pivot row
  __shared__ double ckb[2][128];  // column k (A[r][k]) per row
  const int tid = threadIdx.x;
  const int r  = tid >> 2;        // row 0..127
  const int cg = tid & 3;         // col group
  const int c0 = cg * 32;
  double a[32];
#pragma unroll
  for (int jj = 0; jj < 32; ++jj) a[jj] = Ba[r * 256 + c0 + jj];
#pragma unroll 1
  for (int k = 0; k < 128; ++k) {
    const int par = k & 1;
    const int ke = k >> 5;        // owning col-group of col k
    const int kj = k & 31;        // slot within that group
    if (r == k) {
#pragma unroll
      for (int jj = 0; jj < 32; ++jj) pr[par][c0 + jj] = a[jj];
    }
    if (cg == ke) {
      double ck = a[0];
#pragma unroll
      for (int jj = 1; jj < 32; ++jj) ck = (jj == kj) ? a[jj] : ck;
      ckb[par][r] = ck;
    }
    __syncthreads();
    double pv  = 1.0 / pr[par][k];
    double fik = ckb[par][r];
    bool  isk  = (r == k);
    double f   = fik * pv;
    double fp  = isk ? (1.0 - pv) : f;
#pragma unroll
    for (int jj = 0; jj < 32; ++jj) a[jj] -= fp * pr[par][c0 + jj];
    if (cg == ke) {
      double nv = isk ? pv : -f;
#pragma unroll
      for (int jj = 0; jj < 32; ++jj) if (jj == kj) a[jj] = nv;
    }
  }
#pragma unroll
  for (int jj = 0; jj < 32; ++jj) Ba[r * 256 + 128 + c0 + jj] = a[jj];
}

// ---------------- J[z,t] = Z^T rhs_t  (from normalized GC, v) ----------------
__global__ void k_J(const double* __restrict__ GC, const double* __restrict__ v,
                    const float* __restrict__ q, double* __restrict__ J) {
  int t = blockIdx.x * 16 + threadIdx.x;
  int z = blockIdx.y * 16 + threadIdx.y;
  double val;
  if (t < 128) {
    val = 2.0 * (double)q[t & 3] * GC[(256 + t) * 128 + z];
    if (t >= 124) val += v[(128 + t - 124) * 128 + z];
  } else if (t < 192) {
    val = v[(t - 128) * 128 + z];
  } else {
    val = v[(64 + t - 192) * 128 + z];
  }
  J[z * 256 + t] = val;
}

// ---------------- F = Binv @ J ----------------
__global__ void k_F(const double* __restrict__ Baug, const double* __restrict__ J,
                    double* __restrict__ F) {
  int t = blockIdx.x * 16 + threadIdx.x;
  int z = blockIdx.y * 16 + threadIdx.y;
  double a0 = 0.0, a1 = 0.0;
  for (int w = 0; w < 128; w += 2) {
    a0 += Baug[z * 256 + 128 + w] * J[w * 256 + t];
    a1 += Baug[z * 256 + 128 + w + 1] * J[(w + 1) * 256 + t];
  }
  F[z * 256 + t] = a0 + a1;
}

// ---------------- CEt = (c @ F)^T  (stored 256t x 384i for vectorized k_Egt loads) ----------------
__global__ void k_CE(const double* __restrict__ c, const double* __restrict__ F,
                     double* __restrict__ CEt) {
  int i = blockIdx.x * 16 + threadIdx.x;   // 0..383 (lane dim -> coalesced writes)
  int t = blockIdx.y * 16 + threadIdx.y;   // 0..255
  double a0 = 0.0, a1 = 0.0;
  for (int z = 0; z < 128; z += 2) {
    a0 += c[i * 128 + z] * F[z * 256 + t];
    a1 += c[i * 128 + z + 1] * F[(z + 1) * 256 + t];
  }
  CEt[t * 384 + i] = a0 + a1;
}

// ---------------- E g-map (bf16 hi/lo planes): E[t,c] = sum_i CEt[t,i] * W[i,c] ----------------
// Hankel structure: for fixed c, W[i,c] = sig[4c + i] (i<192, ud) / sig[6000+4c+(i-192)] (yd)
// -> the i-axis is CONTIGUOUS in the signal. float4 LDS reads give 4 i's per ds_read_b128
// (consecutive lane addresses -> no bank conflicts); CEt rows are contiguous -> double2 loads.
__global__ void k_Egt(const double* __restrict__ CEt, const float* __restrict__ ud,
                      const float* __restrict__ yd, unsigned short* __restrict__ Eh,
                      unsigned short* __restrict__ El) {
  __shared__ float sig[12000];
  int tid = threadIdx.y * 16 + threadIdx.x;
  for (int idx = tid; idx < 6000; idx += 256) { sig[idx] = ud[idx]; sig[6000 + idx] = yd[idx]; }
  __syncthreads();
  int c = blockIdx.x * 16 + threadIdx.x;   // < 1536
  int t = blockIdx.y * 16 + threadIdx.y;   // < 256
  double a0 = 0.0, a1 = 0.0, a2 = 0.0, a3 = 0.0;
  if (c < COLS_) {
    const double* ce = &CEt[(size_t)t * 384];
    const float*  su = &sig[4 * c];
    const float*  sy = &sig[6000 + 4 * c];
#pragma unroll 4
    for (int i0 = 0; i0 < 192; i0 += 8) {
      float4 s0 = *(const float4*)&su[i0];
      float4 s1 = *(const float4*)&su[i0 + 4];
      double2 c0 = *(const double2*)&ce[i0];
      double2 c1 = *(const double2*)&ce[i0 + 2];
      double2 c2 = *(const double2*)&ce[i0 + 4];
      double2 c3 = *(const double2*)&ce[i0 + 6];
      a0 += c0.x * (double)s0.x;  a1 += c0.y * (double)s0.y;
      a2 += c1.x * (double)s0.z;  a3 += c1.y * (double)s0.w;
      a0 += c2.x * (double)s1.x;  a1 += c2.y * (double)s1.y;
      a2 += c3.x * (double)s1.z;  a3 += c3.y * (double)s1.w;
    }
    const double* cey = ce + 192;
#pragma unroll 4
    for (int i0 = 0; i0 < 192; i0 += 8) {
      float4 s0 = *(const float4*)&sy[i0];
      float4 s1 = *(const float4*)&sy[i0 + 4];
      double2 c0 = *(const double2*)&cey[i0];
      double2 c1 = *(const double2*)&cey[i0 + 2];
      double2 c2 = *(const double2*)&cey[i0 + 4];
      double2 c3 = *(const double2*)&cey[i0 + 6];
      a0 += c0.x * (double)s0.x;  a1 += c0.y * (double)s0.y;
      a2 += c1.x * (double)s0.z;  a3 += c1.y * (double)s0.w;
      a0 += c2.x * (double)s1.x;  a1 += c2.y * (double)s1.y;
      a2 += c3.x * (double)s1.z;  a3 += c3.y * (double)s1.w;
    }
  }
  double s = (a0 + a1) + (a2 + a3);
  float f = (float)s;
  unsigned short h = f2bf(f);
  float lo = (float)(s - (double)bf2f(h));
  Eh[t * EGS + c] = h;
  El[t * EGS + c] = f2bf(lo);
}

// ---------------- E u/y maps: cols 1536..1791 ----------------
__global__ void k_Euy(const double* __restrict__ GC, const double* __restrict__ F,
                      unsigned short* __restrict__ Eh, unsigned short* __restrict__ El) {
  int n = blockIdx.x * 16 + threadIdx.x;   // 256
  int t = blockIdx.y * 16 + threadIdx.y;   // 256
  int row = (n < 128) ? (64 + n) : (128 + n);   // Uf rows 64..191 ; Yf rows 256..383
  double a0 = 0.0, a1 = 0.0;
  for (int z = 0; z < 128; z += 2) {
    a0 += GC[row * 128 + z] * F[z * 256 + t];
    a1 += GC[row * 128 + z + 1] * F[(z + 1) * 256 + t];
  }
  double s = a0 + a1;
  float f = (float)s;
  unsigned short h = f2bf(f);
  float lo = (float)(s - (double)bf2f(h));
  Eh[t * EGS + 1536 + n] = h;
  El[t * EGS + 1536 + n] = f2bf(lo);
}

// ---------------- A-operand loader ----------------
__device__ __forceinline__ float4 loadA4(const float* __restrict__ ref, const float* __restrict__ ui,
                                         const float* __restrict__ yi, int m, int j) {
  if (j < 128) return *(const float4*)&ref[m * 128 + j];
  if (j < 192) return *(const float4*)&ui[m * 64 + (j - 128)];
  return *(const float4*)&yi[m * 64 + (j - 192)];
}

// ---------------- gemm1 (MFMA bf16 3-term split): [g|u|y] = Xin(8192x256) @ E(256x1792) ----------------
// C = Xh*Eh + Xh*El + Xl*Eh on mfma_f32_16x16x32_bf16.  (R5-proven version: LDS-staged,
// T14 async register prefetch, cvt_pk split. R6's LDS-free variant regressed -> reverted.)
__global__ __launch_bounds__(256, 2) void k_gemm1(const float* __restrict__ ref, const float* __restrict__ ui,
                                                  const float* __restrict__ yi,
                                                  const unsigned short* __restrict__ Eh,
                                                  const unsigned short* __restrict__ El,
                                                  float* __restrict__ gout, float* __restrict__ uout,
                                                  float* __restrict__ yout) {
  __shared__ unsigned short Ah[128 * 32];   // 8 KB each
  __shared__ unsigned short Al[128 * 32];
  __shared__ unsigned short Bh[128 * 32];
  __shared__ unsigned short Bl[128 * 32];
  const int tid = threadIdx.x;
  const int m0 = blockIdx.y * 128;
  const int n0 = blockIdx.x * 128;
  const int w  = tid >> 6;
  const int lane = tid & 63;
  const int wm = (w >> 1) * 64;       // wave M offset within block
  const int wn = (w & 1) * 64;        // wave N offset
  const int fr = lane & 15;           // frag row (A) / col (B,D)
  const int kg = lane >> 4;           // frag k-group 0..3
  // staging mapping
  const int sRow = tid & 127;         // A row / B col
  const int sKh  = tid >> 7;          // k half (16 k's)
  const int sXor = (sRow >> 1) & 3;   // k-segment XOR for this row/col

  v4f acc[4][4];
#pragma unroll
  for (int i = 0; i < 4; ++i)
#pragma unroll
    for (int j = 0; j < 4; ++j) acc[i][j] = (v4f){0.0f, 0.0f, 0.0f, 0.0f};

  // prefetch registers (live across the MFMA phase)
  float4 q0, q1, q2, q3;
  unsigned short eh[16], el[16];

  // ---- issue chunk-0 loads
  {
    const int jb = sKh * 16;
    q0 = loadA4(ref, ui, yi, m0 + sRow, jb + 0);
    q1 = loadA4(ref, ui, yi, m0 + sRow, jb + 4);
    q2 = loadA4(ref, ui, yi, m0 + sRow, jb + 8);
    q3 = loadA4(ref, ui, yi, m0 + sRow, jb + 12);
#pragma unroll
    for (int e = 0; e < 16; ++e) {
      int idx = (jb + e) * EGS + n0 + sRow;
      eh[e] = Eh[idx];
      el[e] = El[idx];
    }
  }

  for (int k0 = 0; k0 < 256; k0 += 32) {
    // ---- convert prefetched regs: X -> bf16 hi/lo via v_cvt_pk_bf16_f32
    float xa[16] = {q0.x, q0.y, q0.z, q0.w, q1.x, q1.y, q1.z, q1.w,
                    q2.x, q2.y, q2.z, q2.w, q3.x, q3.y, q3.z, q3.w};
    union { v8s s; unsigned u[4]; } ah0, ah1, al0, al1;
#pragma unroll
    for (int p = 0; p < 8; ++p) {
      float x0 = xa[2 * p], x1 = xa[2 * p + 1];
      unsigned hp, lp;
      asm("v_cvt_pk_bf16_f32 %0, %1, %2" : "=v"(hp) : "v"(x0), "v"(x1));
      union { unsigned u; float f; } h0, h1;
      h0.u = hp << 16;
      h1.u = hp & 0xFFFF0000u;
      float l0 = x0 - h0.f;       // exact (Sterbenz: h within 2^-8 of x)
      float l1 = x1 - h1.f;
      asm("v_cvt_pk_bf16_f32 %0, %1, %2" : "=v"(lp) : "v"(l0), "v"(l1));
      if (p < 4) { ah0.u[p] = hp; al0.u[p] = lp; }
      else       { ah1.u[p - 4] = hp; al1.u[p - 4] = lp; }
    }
    v8s bh0, bh1, bl0, bl1;
#pragma unroll
    for (int e = 0; e < 8; ++e) {
      bh0[e] = (short)eh[e];
      bh1[e] = (short)eh[8 + e];
      bl0[e] = (short)el[e];
      bl1[e] = (short)el[8 + e];
    }
    __syncthreads();   // previous chunk's compute done -> safe to overwrite LDS
    {
      const int s0 = ((sKh * 2 + 0) ^ sXor) * 8;
      const int s1 = ((sKh * 2 + 1) ^ sXor) * 8;
      *(v8s*)&Ah[sRow * 32 + s0] = ah0.s;
      *(v8s*)&Ah[sRow * 32 + s1] = ah1.s;
      *(v8s*)&Al[sRow * 32 + s0] = al0.s;
      *(v8s*)&Al[sRow * 32 + s1] = al1.s;
      *(v8s*)&Bh[sRow * 32 + s0] = bh0;
      *(v8s*)&Bh[sRow * 32 + s1] = bh1;
      *(v8s*)&Bl[sRow * 32 + s0] = bl0;
      *(v8s*)&Bl[sRow * 32 + s1] = bl1;
    }
    __syncthreads();
    // ---- T14: issue NEXT chunk's global loads now; latency hides under frag+MFMA
    if (k0 < 224) {
      const int jb = k0 + 32 + sKh * 16;
      q0 = loadA4(ref, ui, yi, m0 + sRow, jb + 0);
      q1 = loadA4(ref, ui, yi, m0 + sRow, jb + 4);
      q2 = loadA4(ref, ui, yi, m0 + sRow, jb + 8);
      q3 = loadA4(ref, ui, yi, m0 + sRow, jb + 12);
#pragma unroll
      for (int e = 0; e < 16; ++e) {
        int idx = (jb + e) * EGS + n0 + sRow;
        eh[e] = Eh[idx];
        el[e] = El[idx];
      }
    }
    // ---- fragments + 48 MFMA
    v8s fah[4], fal[4], fbh[4], fbl[4];
#pragma unroll
    for (int t4 = 0; t4 < 4; ++t4) {
      int ar = wm + t4 * 16 + fr;
      int as = (kg ^ ((ar >> 1) & 3)) * 8;
      fah[t4] = *(const v8s*)&Ah[ar * 32 + as];
      fal[t4] = *(const v8s*)&Al[ar * 32 + as];
      int bc = wn + t4 * 16 + fr;
      int bs = (kg ^ ((bc >> 1) & 3)) * 8;
      fbh[t4] = *(const v8s*)&Bh[bc * 32 + bs];
      fbl[t4] = *(const v8s*)&Bl[bc * 32 + bs];
    }
#pragma unroll
    for (int tm = 0; tm < 4; ++tm)
#pragma unroll
      for (int tn = 0; tn < 4; ++tn) {
        acc[tm][tn] = __builtin_amdgcn_mfma_f32_16x16x32_bf16(fal[tm], fbh[tn], acc[tm][tn], 0, 0, 0);
        acc[tm][tn] = __builtin_amdgcn_mfma_f32_16x16x32_bf16(fah[tm], fbl[tn], acc[tm][tn], 0, 0, 0);
        acc[tm][tn] = __builtin_amdgcn_mfma_f32_16x16x32_bf16(fah[tm], fbh[tn], acc[tm][tn], 0, 0, 0);
      }
  }
  // ---- epilogue: D lane mapping col=l&15, row=(l>>4)*4+r
#pragma unroll
  for (int tm = 0; tm < 4; ++tm) {
    const int mb = m0 + wm + tm * 16 + kg * 4;
#pragma unroll
    for (int tn = 0; tn < 4; ++tn) {
      const int n = n0 + wn + tn * 16 + fr;
#pragma unroll
      for (int r = 0; r < 4; ++r) {
        float vv = acc[tm][tn][r];
        int m = mb + r;
        if (n < COLS_)       gout[(size_t)m * COLS_ + n] = vv;
        else if (n >= 1664)  yout[m * 128 + (n - 1664)] = vv;
        else if (n >= 1536)  uout[m * 128 + (n - 1536)] = vv;
      }
    }
  }
}

extern "C" void kernel_launch(void* const* d_in, const int* in_sizes, int n_in,
                              void* d_out, int out_size, void* d_ws, size_t ws_size,
                              hipStream_t stream) {
  (void)in_sizes; (void)n_in; (void)out_size; (void)ws_size;
  const float* ref   = (const float*)d_in[0];
  const float* u_ini = (const float*)d_in[2];
  const float* y_ini = (const float*)d_in[3];
  const float* ud    = (const float*)d_in[4];
  const float* yd    = (const float*)d_in[5];
  const float* q     = (const float*)d_in[6];
  const float* r     = (const float*)d_in[7];

  float* out  = (float*)d_out;
  float* gout = out;
  float* uout = out + (size_t)NB * COLS_;
  float* yout = uout + (size_t)NB * 128;

  double* Wd  = (double*)d_out;
  double* Gam = Wd + oGam;
  double* c   = Wd + oC;
  double* v   = Wd + oV;
  double* GC  = Wd + oGC;
  double* cK  = Wd + oCK;
  double* vK  = Wd + oVK;
  double* GCK = Wd + oGCK;
  double* Ba  = Wd + oB;
  double* J   = Wd + oJ;
  double* F   = Wd + oF;
  double* CEt = Wd + oCE;
  unsigned short* Eh = (unsigned short*)d_ws;              // 256x1792 bf16 hi plane
  unsigned short* El = Eh + (size_t)256 * EGS;             // 256x1792 bf16 lo plane

  // 1) Gram matrix (the only 1453-deep f64 kernel)
  k_gram<<<dim3(24, 24), dim3(16, 16), 0, stream>>>(ud, yd, Gam);

  // 2) block power iteration for the dominant-128 subspace, in 384+132 coordinates
  k_initc<<<dim3(8, 33), dim3(16, 16), 0, stream>>>(c, v);
  double* ca = c;  double* va = v;
  double* cb = cK; double* vb = vK;
  for (int it = 0; it < 4; ++it) {
    k_G<<<dim3(8, 24), dim3(16, 16), 0, stream>>>(Gam, ca, GC);
    k_step<<<dim3(8, 33), dim3(16, 16), 0, stream>>>(GC, va, q, r, cb, vb);
    double* t1 = ca; ca = cb; cb = t1;
    double* t2 = va; va = vb; vb = t2;
  }
  // ca/va hold the iterate (== c/v buffers after 4 swaps)

  // 3) normalize; KZ in coordinates; B = Z^T K Z
  k_G<<<dim3(8, 24), dim3(16, 16), 0, stream>>>(Gam, ca, GC);
  k_normc<<<128, 256, 0, stream>>>(ca, va, GC);
  k_step<<<dim3(8, 33), dim3(16, 16), 0, stream>>>(GC, va, q, r, cb, vb);
  k_G<<<dim3(8, 24), dim3(16, 16), 0, stream>>>(Gam, cb, GCK);
  k_B<<<dim3(16, 8), dim3(16, 16), 0, stream>>>(ca, GCK, va, vb, Ba);

  // 4) invert B (128x128) in ONE single-workgroup register GJ; writes the inverse
  //    into Baug cols 128..255 (what k_F reads). Replaces 2x(k_inv64+rowscale+update).
  k_inv128<<<1, 512, 0, stream>>>(Ba);

  // 5) input->coefficient map and the three output maps (bf16 hi/lo planes)
  k_J<<<dim3(16, 8), dim3(16, 16), 0, stream>>>(GC, va, q, J);
  k_F<<<dim3(16, 8), dim3(16, 16), 0, stream>>>(Ba, J, F);
  k_CE<<<dim3(24, 16), dim3(16, 16), 0, stream>>>(ca, F, CEt);
  k_Egt<<<dim3(96, 16), dim3(16, 16), 0, stream>>>(CEt, ud, yd, Eh, El);
  k_Euy<<<dim3(16, 16), dim3(16, 16), 0, stream>>>(GC, F, Eh, El);

  // 6) one batch MFMA GEMM produces g, u, y
  k_gemm1<<<dim3(14, 64), dim3(256), 0, stream>>>(ref, u_ini, y_ini, Eh, El, gout, uout, yout);
}

// Round 8
// 546.733 us; speedup vs baseline: 1.4513x; 1.4513x over previous
//
#include <hip/hip_runtime.h>

// Problem constants
#define COLS_ 1453
#define NC 132
#define EGS 1792       // E row stride: [g-map 0..1535 | u-map 1536..1663 | y-map 1664..1791]
#define NB 8192

// f64 scratch offsets (doubles) in d_out g-region (dead before gemm1 writes g).
// W rows: 0..63 Up(ud), 64..191 Uf(ud), 192..255 Yp(yd), 256..383 Yf(yd).
#define oGam 0          // Gamma 384x384
#define oC   147456     // c    384x128
#define oV   196608     // v    132x128
#define oGC  213504     // Gamma*c 384x128
#define oCK  262656     // cK   384x128
#define oVK  311808     // vK   132x128
#define oGCK 328704     // Gamma*cK 384x128
#define oB   377856     // [B|I] 128x256
#define oP   410624     // 64x64 pivot inverse
#define oR   414980     // 64x256
#define oJ   431364     // 128x256
#define oF   464132     // 128x256
#define oCE  496900     // CEt 256x384 (transposed)   (end 595204 dbl = 4.76 MB)
// Eh/El (bf16 256x1792 each = 1.79 MB total) live in d_ws (R4-proven region).

typedef short v8s __attribute__((ext_vector_type(8)));    // 8 bf16 (4 VGPRs)
typedef float v4f __attribute__((ext_vector_type(4)));    // MFMA acc

__device__ __forceinline__ double hash01(unsigned i, unsigned j) {
  unsigned x = i * 0x9E3779B9u ^ (j * 0x85EBCA6Bu + 0xC2B2AE35u);
  x ^= x >> 16; x *= 0x7FEB352Du; x ^= x >> 15; x *= 0x846CA68Bu; x ^= x >> 16;
  return (double)(x & 0xFFFFFF) / 8388608.0 - 1.0;
}

// bf16 helpers (RNE)
__device__ __forceinline__ unsigned short f2bf(float x) {
  union { float f; unsigned u; } v; v.f = x;
  unsigned r = (v.u + 0x7FFFu + ((v.u >> 16) & 1u)) >> 16;
  return (unsigned short)r;
}
__device__ __forceinline__ float bf2f(unsigned short h) {
  union { unsigned u; float f; } v; v.u = ((unsigned)h) << 16; return v.f;
}

// ---------------- Gram: Gamma = W W^T  (R2-proven structure, +ILP) ----------------
__global__ void k_gram(const float* __restrict__ ud, const float* __restrict__ yd,
                       double* __restrict__ G) {
  __shared__ float sig[12000];
  int tid = threadIdx.y * 16 + threadIdx.x;
  for (int idx = tid; idx < 6000; idx += 256) { sig[idx] = ud[idx]; sig[6000 + idx] = yd[idx]; }
  __syncthreads();
  int i = blockIdx.y * 16 + threadIdx.y;
  int j = blockIdx.x * 16 + threadIdx.x;
  const float* si = &sig[(i < 192) ? i : (6000 + i - 192)];
  const float* sj = &sig[(j < 192) ? j : (6000 + j - 192)];
  double a0 = 0.0, a1 = 0.0, a2 = 0.0, a3 = 0.0;
  for (int c = 0; c < 1452; c += 4) {
    a0 += (double)si[4 * c]      * (double)sj[4 * c];
    a1 += (double)si[4 * c + 4]  * (double)sj[4 * c + 4];
    a2 += (double)si[4 * c + 8]  * (double)sj[4 * c + 8];
    a3 += (double)si[4 * c + 12] * (double)sj[4 * c + 12];
  }
  a0 += (double)si[4 * 1452] * (double)sj[4 * 1452];
  G[i * 384 + j] = (a0 + a1) + (a2 + a3);
}

// ---------------- init c (384x128) and v (132x128) ----------------
__global__ void k_initc(double* __restrict__ c, double* __restrict__ v) {
  int z = blockIdx.x * 16 + threadIdx.x;
  int i = blockIdx.y * 16 + threadIdx.y;
  if (i < 384) c[i * 128 + z] = hash01(i, z);
  else if (i < 516) v[(i - 384) * 128 + z] = hash01(i + 1000, z);
}

// ---------------- GC = Gamma @ c  (384x128) ----------------
__global__ void k_G(const double* __restrict__ Gam, const double* __restrict__ c,
                    double* __restrict__ outp) {
  int z = blockIdx.x * 16 + threadIdx.x;
  int i = blockIdx.y * 16 + threadIdx.y;
  double a0 = 0.0, a1 = 0.0;
  for (int t = 0; t < 384; t += 2) {
    a0 += Gam[i * 384 + t]     * c[t * 128 + z];
    a1 += Gam[i * 384 + t + 1] * c[(t + 1) * 128 + z];
  }
  outp[i * 128 + z] = a0 + a1;
}

// ---------------- FUSED power-iteration step: (Gam, c, v) -> (cK, vK) ----------------
// Computes s = (Gamma@c)[i,z] in-register (bit-identical to k_G), then applies the
// k_step mapping element-wise. vK rows are sourced exactly from GC rows
// {0..63 -> vK[0..63], 192..255 -> vK[64..127], 380..383 -> vK[128..131]}, so the
// block computing that element writes it. GC itself is never materialized (it was
// only consumed by k_step within the iteration loop).
__global__ void k_Gstep(const double* __restrict__ Gam, const double* __restrict__ c,
                        const double* __restrict__ v, const float* __restrict__ q,
                        const float* __restrict__ r, double* __restrict__ cK,
                        double* __restrict__ vK) {
  int z = blockIdx.x * 16 + threadIdx.x;
  int i = blockIdx.y * 16 + threadIdx.y;     // 0..383
  double a0 = 0.0, a1 = 0.0;
  for (int t = 0; t < 384; t += 2) {
    a0 += Gam[i * 384 + t]     * c[t * 128 + z];
    a1 += Gam[i * 384 + t + 1] * c[(t + 1) * 128 + z];
  }
  double s = a0 + a1;
  // cK mapping (identical to k_step with GC[i,z] == s)
  double val;
  if (i < 64)        val = v[i * 128 + z];
  else if (i < 192)  { int m = i - 64;  val = 2.0 * (double)r[m & 3] * s; }
  else if (i < 256)  val = v[(64 + i - 192) * 128 + z];
  else {
    int m = i - 256;
    val = 2.0 * (double)q[m & 3] * s;
    if (m >= 124) val += v[(128 + m - 124) * 128 + z];
  }
  cK[i * 128 + z] = val;
  // vK entries sourced from this GC element
  if (i < 64)                    vK[i * 128 + z] = s;
  else if (i >= 192 && i < 256)  vK[(64 + i - 192) * 128 + z] = s;
  else if (i >= 380)             vK[(128 + i - 380) * 128 + z] = s;
}

// ---------------- K-apply in coordinates: (GC, v) -> (cK, vK) ----------------
__global__ void k_step(const double* __restrict__ GC, const double* __restrict__ v,
                       const float* __restrict__ q, const float* __restrict__ r,
                       double* __restrict__ cK, double* __restrict__ vK) {
  int z = blockIdx.x * 16 + threadIdx.x;
  int i = blockIdx.y * 16 + threadIdx.y;
  if (i >= 516) return;
  if (i < 384) {
    double val;
    if (i < 64)        val = v[i * 128 + z];                                   // A^T v, Up rows
    else if (i < 192)  { int m = i - 64;  val = 2.0 * (double)r[m & 3] * GC[i * 128 + z]; }
    else if (i < 256)  val = v[(64 + i - 192) * 128 + z];                      // A^T v, Yp rows
    else {
      int m = i - 256;
      val = 2.0 * (double)q[m & 3] * GC[i * 128 + z];
      if (m >= 124) val += v[(128 + m - 124) * 128 + z];                        // terminal rows
    }
    cK[i * 128 + z] = val;
  } else {
    int rr = i - 384;
    double val;
    if (rr < 64)       val = GC[rr * 128 + z];                                 // Up g
    else if (rr < 128) val = GC[(192 + rr - 64) * 128 + z];                    // Yp g
    else               val = GC[(380 + rr - 128) * 128 + z];                   // Yf last 4
    vK[rr * 128 + z] = val;
  }
}

// ---------------- normalize columns: scale c, v, GC by 1/||z|| ----------------
__global__ void k_normc(double* __restrict__ c, double* __restrict__ v, double* __restrict__ GC) {
  __shared__ double red[256];
  int z = blockIdx.x, tid = threadIdx.x;
  double s = 0.0;
  for (int i = tid; i < 384; i += 256) s += c[i * 128 + z] * GC[i * 128 + z];
  for (int rr = tid; rr < 132; rr += 256) { double t = v[rr * 128 + z]; s += t * t; }
  red[tid] = s; __syncthreads();
  for (int st = 128; st > 0; st >>= 1) { if (tid < st) red[tid] += red[tid + st]; __syncthreads(); }
  double inv = rsqrt(red[0]);
  for (int i = tid; i < 384; i += 256) { c[i * 128 + z] *= inv; GC[i * 128 + z] *= inv; }
  for (int rr = tid; rr < 132; rr += 256) v[rr * 128 + z] *= inv;
}

// ---------------- Baug = [ c^T GCK + v^T vK | I ]  (128x256) ----------------
__global__ void k_B(const double* __restrict__ c, const double* __restrict__ GCK,
                    const double* __restrict__ v, const double* __restrict__ vK,
                    double* __restrict__ Baug) {
  int z2 = blockIdx.x * 16 + threadIdx.x;
  int z1 = blockIdx.y * 16 + threadIdx.y;
  if (z2 >= 128) { Baug[z1 * 256 + z2] = ((z2 - 128) == z1) ? 1.0 : 0.0; return; }
  double a0 = 0.0, a1 = 0.0;
  for (int i = 0; i < 384; i += 2) {
    a0 += c[i * 128 + z1] * GCK[i * 128 + z2];
    a1 += c[(i + 1) * 128 + z1] * GCK[(i + 1) * 128 + z2];
  }
  for (int rr = 0; rr < 132; ++rr) a0 += v[rr * 128 + z1] * vK[rr * 128 + z2];
  Baug[z1 * 256 + z2] = a0 + a1;
}

// ---------------- distributed-register GJ inverse (64x64, 512 threads; a[8] HW-proven) ----------------
__global__ __launch_bounds__(512) void k_inv(const double* __restrict__ src, int srcStride,
                                             double* __restrict__ dst, int n) {
  (void)n;  // always 64
  __shared__ double pr[2][64];   // unscaled pivot row
  __shared__ double ckb[2][64];  // column k (A[r][k]), per row
  const int tid = threadIdx.x;
  const int r  = tid >> 3;       // row 0..63
  const int cg = tid & 7;        // column lane: owns cols jj*8+cg
  double a[8];
#pragma unroll
  for (int jj = 0; jj < 8; ++jj) a[jj] = src[r * srcStride + jj * 8 + cg];
#pragma unroll 1
  for (int k = 0; k < 64; ++k) {
    const int par = k & 1;
    const int ke = k & 7;        // column-owner lane
    const int kj = k >> 3;       // register slot of column k
    if (r == k) {
#pragma unroll
      for (int jj = 0; jj < 8; ++jj) pr[par][jj * 8 + cg] = a[jj];
    }
    if (cg == ke) {
#pragma unroll
      for (int jj = 0; jj < 8; ++jj) if (jj == kj) ckb[par][r] = a[jj];
    }
    __syncthreads();
    double pv  = 1.0 / pr[par][k];
    double fik = ckb[par][r];
    bool  isk  = (r == k);
    double f   = fik * pv;
    double fp  = isk ? (1.0 - pv) : f;
#pragma unroll
    for (int jj = 0; jj < 8; ++jj) a[jj] -= fp * pr[par][jj * 8 + cg];
    if (cg == ke) {
#pragma unroll
      for (int jj = 0; jj < 8; ++jj) if (jj == kj) a[jj] = isk ? pv : -f;
    }
  }
#pragma unroll
  for (int jj = 0; jj < 8; ++jj) dst[r * 64 + jj * 8 + cg] = a[jj];
}

__global__ void k_rowscale(const double* __restrict__ Maug, const double* __restrict__ P,
                           double* __restrict__ R, int stride, int nb, int k) {
  int c = nb * (k + 1) + blockIdx.x * 64 + threadIdx.x;
  if (c >= stride) return;
  int rr = blockIdx.y;
  double acc = 0.0;
  for (int t = 0; t < nb; ++t) acc += P[rr * nb + t] * Maug[(nb * k + t) * stride + c];
  R[rr * stride + c] = acc;
}

__global__ void k_update(double* __restrict__ Maug, const double* __restrict__ R,
                         int stride, int n, int nb, int k) {
  int c = nb * (k + 1) + blockIdx.x * 64 + threadIdx.x;
  if (c >= stride) return;
  int i = blockIdx.y;
  int ib = i - nb * k;
  if (ib >= 0 && ib < nb) { Maug[i * stride + c] = R[ib * stride + c]; return; }
  double acc = Maug[i * stride + c];
  for (int t = 0; t < nb; ++t) acc -= Maug[i * stride + nb * k + t] * R[t * stride + c];
  Maug[i * stride + c] = acc;
}

// ---------------- J[z,t] = Z^T rhs_t  (from normalized GC, v) ----------------
__global__ void k_J(const double* __restrict__ GC, const double* __restrict__ v,
                    const float* __restrict__ q, double* __restrict__ J) {
  int t = blockIdx.x * 16 + threadIdx.x;
  int z = blockIdx.y * 16 + threadIdx.y;
  double val;
  if (t < 128) {
    val = 2.0 * (double)q[t & 3] * GC[(256 + t) * 128 + z];
    if (t >= 124) val += v[(128 + t - 124) * 128 + z];
  } else if (t < 192) {
    val = v[(t - 128) * 128 + z];
  } else {
    val = v[(64 + t - 192) * 128 + z];
  }
  J[z * 256 + t] = val;
}

// ---------------- F = Binv @ J ----------------
__global__ void k_F(const double* __restrict__ Baug, const double* __restrict__ J,
                    double* __restrict__ F) {
  int t = blockIdx.x * 16 + threadIdx.x;
  int z = blockIdx.y * 16 + threadIdx.y;
  double a0 = 0.0, a1 = 0.0;
  for (int w = 0; w < 128; w += 2) {
    a0 += Baug[z * 256 + 128 + w] * J[w * 256 + t];
    a1 += Baug[z * 256 + 128 + w + 1] * J[(w + 1) * 256 + t];
  }
  F[z * 256 + t] = a0 + a1;
}

// ---------------- CEt = (c @ F)^T  (stored 256t x 384i for vectorized k_Egt loads) ----------------
__global__ void k_CE(const double* __restrict__ c, const double* __restrict__ F,
                     double* __restrict__ CEt) {
  int i = blockIdx.x * 16 + threadIdx.x;   // 0..383 (lane dim -> coalesced writes)
  int t = blockIdx.y * 16 + threadIdx.y;   // 0..255
  double a0 = 0.0, a1 = 0.0;
  for (int z = 0; z < 128; z += 2) {
    a0 += c[i * 128 + z] * F[z * 256 + t];
    a1 += c[i * 128 + z + 1] * F[(z + 1) * 256 + t];
  }
  CEt[t * 384 + i] = a0 + a1;
}

// ---------------- E g-map (bf16 hi/lo planes): E[t,c] = sum_i CEt[t,i] * W[i,c] ----------------
__global__ void k_Egt(const double* __restrict__ CEt, const float* __restrict__ ud,
                      const float* __restrict__ yd, unsigned short* __restrict__ Eh,
                      unsigned short* __restrict__ El) {
  __shared__ float sig[12000];
  int tid = threadIdx.y * 16 + threadIdx.x;
  for (int idx = tid; idx < 6000; idx += 256) { sig[idx] = ud[idx]; sig[6000 + idx] = yd[idx]; }
  __syncthreads();
  int c = blockIdx.x * 16 + threadIdx.x;   // < 1536
  int t = blockIdx.y * 16 + threadIdx.y;   // < 256
  double a0 = 0.0, a1 = 0.0, a2 = 0.0, a3 = 0.0;
  if (c < COLS_) {
    const double* ce = &CEt[(size_t)t * 384];
    const float*  su = &sig[4 * c];
    const float*  sy = &sig[6000 + 4 * c];
#pragma unroll 4
    for (int i0 = 0; i0 < 192; i0 += 8) {
      float4 s0 = *(const float4*)&su[i0];
      float4 s1 = *(const float4*)&su[i0 + 4];
      double2 c0 = *(const double2*)&ce[i0];
      double2 c1 = *(const double2*)&ce[i0 + 2];
      double2 c2 = *(const double2*)&ce[i0 + 4];
      double2 c3 = *(const double2*)&ce[i0 + 6];
      a0 += c0.x * (double)s0.x;  a1 += c0.y * (double)s0.y;
      a2 += c1.x * (double)s0.z;  a3 += c1.y * (double)s0.w;
      a0 += c2.x * (double)s1.x;  a1 += c2.y * (double)s1.y;
      a2 += c3.x * (double)s1.z;  a3 += c3.y * (double)s1.w;
    }
    const double* cey = ce + 192;
#pragma unroll 4
    for (int i0 = 0; i0 < 192; i0 += 8) {
      float4 s0 = *(const float4*)&sy[i0];
      float4 s1 = *(const float4*)&sy[i0 + 4];
      double2 c0 = *(const double2*)&cey[i0];
      double2 c1 = *(const double2*)&cey[i0 + 2];
      double2 c2 = *(const double2*)&cey[i0 + 4];
      double2 c3 = *(const double2*)&cey[i0 + 6];
      a0 += c0.x * (double)s0.x;  a1 += c0.y * (double)s0.y;
      a2 += c1.x * (double)s0.z;  a3 += c1.y * (double)s0.w;
      a0 += c2.x * (double)s1.x;  a1 += c2.y * (double)s1.y;
      a2 += c3.x * (double)s1.z;  a3 += c3.y * (double)s1.w;
    }
  }
  double s = (a0 + a1) + (a2 + a3);
  float f = (float)s;
  unsigned short h = f2bf(f);
  float lo = (float)(s - (double)bf2f(h));
  Eh[t * EGS + c] = h;
  El[t * EGS + c] = f2bf(lo);
}

// ---------------- E u/y maps: cols 1536..1791 ----------------
__global__ void k_Euy(const double* __restrict__ GC, const double* __restrict__ F,
                      unsigned short* __restrict__ Eh, unsigned short* __restrict__ El) {
  int n = blockIdx.x * 16 + threadIdx.x;   // 256
  int t = blockIdx.y * 16 + threadIdx.y;   // 256
  int row = (n < 128) ? (64 + n) : (128 + n);   // Uf rows 64..191 ; Yf rows 256..383
  double a0 = 0.0, a1 = 0.0;
  for (int z = 0; z < 128; z += 2) {
    a0 += GC[row * 128 + z] * F[z * 256 + t];
    a1 += GC[row * 128 + z + 1] * F[(z + 1) * 256 + t];
  }
  double s = a0 + a1;
  float f = (float)s;
  unsigned short h = f2bf(f);
  float lo = (float)(s - (double)bf2f(h));
  Eh[t * EGS + 1536 + n] = h;
  El[t * EGS + 1536 + n] = f2bf(lo);
}

// ---------------- A-operand loader ----------------
__device__ __forceinline__ float4 loadA4(const float* __restrict__ ref, const float* __restrict__ ui,
                                         const float* __restrict__ yi, int m, int j) {
  if (j < 128) return *(const float4*)&ref[m * 128 + j];
  if (j < 192) return *(const float4*)&ui[m * 64 + (j - 128)];
  return *(const float4*)&yi[m * 64 + (j - 192)];
}

// ---------------- gemm1 (MFMA bf16 3-term split): [g|u|y] = Xin(8192x256) @ E(256x1792) ----------------
// R5-proven version: LDS-staged, T14 async register prefetch, cvt_pk split.
__global__ __launch_bounds__(256, 2) void k_gemm1(const float* __restrict__ ref, const float* __restrict__ ui,
                                                  const float* __restrict__ yi,
                                                  const unsigned short* __restrict__ Eh,
                                                  const unsigned short* __restrict__ El,
                                                  float* __restrict__ gout, float* __restrict__ uout,
                                                  float* __restrict__ yout) {
  __shared__ unsigned short Ah[128 * 32];   // 8 KB each
  __shared__ unsigned short Al[128 * 32];
  __shared__ unsigned short Bh[128 * 32];
  __shared__ unsigned short Bl[128 * 32];
  const int tid = threadIdx.x;
  const int m0 = blockIdx.y * 128;
  const int n0 = blockIdx.x * 128;
  const int w  = tid >> 6;
  const int lane = tid & 63;
  const int wm = (w >> 1) * 64;       // wave M offset within block
  const int wn = (w & 1) * 64;        // wave N offset
  const int fr = lane & 15;           // frag row (A) / col (B,D)
  const int kg = lane >> 4;           // frag k-group 0..3
  // staging mapping
  const int sRow = tid & 127;         // A row / B col
  const int sKh  = tid >> 7;          // k half (16 k's)
  const int sXor = (sRow >> 1) & 3;   // k-segment XOR for this row/col

  v4f acc[4][4];
#pragma unroll
  for (int i = 0; i < 4; ++i)
#pragma unroll
    for (int j = 0; j < 4; ++j) acc[i][j] = (v4f){0.0f, 0.0f, 0.0f, 0.0f};

  // prefetch registers (live across the MFMA phase)
  float4 q0, q1, q2, q3;
  unsigned short eh[16], el[16];

  // ---- issue chunk-0 loads
  {
    const int jb = sKh * 16;
    q0 = loadA4(ref, ui, yi, m0 + sRow, jb + 0);
    q1 = loadA4(ref, ui, yi, m0 + sRow, jb + 4);
    q2 = loadA4(ref, ui, yi, m0 + sRow, jb + 8);
    q3 = loadA4(ref, ui, yi, m0 + sRow, jb + 12);
#pragma unroll
    for (int e = 0; e < 16; ++e) {
      int idx = (jb + e) * EGS + n0 + sRow;
      eh[e] = Eh[idx];
      el[e] = El[idx];
    }
  }

  for (int k0 = 0; k0 < 256; k0 += 32) {
    // ---- convert prefetched regs: X -> bf16 hi/lo via v_cvt_pk_bf16_f32
    float xa[16] = {q0.x, q0.y, q0.z, q0.w, q1.x, q1.y, q1.z, q1.w,
                    q2.x, q2.y, q2.z, q2.w, q3.x, q3.y, q3.z, q3.w};
    union { v8s s; unsigned u[4]; } ah0, ah1, al0, al1;
#pragma unroll
    for (int p = 0; p < 8; ++p) {
      float x0 = xa[2 * p], x1 = xa[2 * p + 1];
      unsigned hp, lp;
      asm("v_cvt_pk_bf16_f32 %0, %1, %2" : "=v"(hp) : "v"(x0), "v"(x1));
      union { unsigned u; float f; } h0, h1;
      h0.u = hp << 16;
      h1.u = hp & 0xFFFF0000u;
      float l0 = x0 - h0.f;       // exact (Sterbenz: h within 2^-8 of x)
      float l1 = x1 - h1.f;
      asm("v_cvt_pk_bf16_f32 %0, %1, %2" : "=v"(lp) : "v"(l0), "v"(l1));
      if (p < 4) { ah0.u[p] = hp; al0.u[p] = lp; }
      else       { ah1.u[p - 4] = hp; al1.u[p - 4] = lp; }
    }
    v8s bh0, bh1, bl0, bl1;
#pragma unroll
    for (int e = 0; e < 8; ++e) {
      bh0[e] = (short)eh[e];
      bh1[e] = (short)eh[8 + e];
      bl0[e] = (short)el[e];
      bl1[e] = (short)el[8 + e];
    }
    __syncthreads();   // previous chunk's compute done -> safe to overwrite LDS
    {
      const int s0 = ((sKh * 2 + 0) ^ sXor) * 8;
      const int s1 = ((sKh * 2 + 1) ^ sXor) * 8;
      *(v8s*)&Ah[sRow * 32 + s0] = ah0.s;
      *(v8s*)&Ah[sRow * 32 + s1] = ah1.s;
      *(v8s*)&Al[sRow * 32 + s0] = al0.s;
      *(v8s*)&Al[sRow * 32 + s1] = al1.s;
      *(v8s*)&Bh[sRow * 32 + s0] = bh0;
      *(v8s*)&Bh[sRow * 32 + s1] = bh1;
      *(v8s*)&Bl[sRow * 32 + s0] = bl0;
      *(v8s*)&Bl[sRow * 32 + s1] = bl1;
    }
    __syncthreads();
    // ---- T14: issue NEXT chunk's global loads now; latency hides under frag+MFMA
    if (k0 < 224) {
      const int jb = k0 + 32 + sKh * 16;
      q0 = loadA4(ref, ui, yi, m0 + sRow, jb + 0);
      q1 = loadA4(ref, ui, yi, m0 + sRow, jb + 4);
      q2 = loadA4(ref, ui, yi, m0 + sRow, jb + 8);
      q3 = loadA4(ref, ui, yi, m0 + sRow, jb + 12);
#pragma unroll
      for (int e = 0; e < 16; ++e) {
        int idx = (jb + e) * EGS + n0 + sRow;
        eh[e] = Eh[idx];
        el[e] = El[idx];
      }
    }
    // ---- fragments + 48 MFMA
    v8s fah[4], fal[4], fbh[4], fbl[4];
#pragma unroll
    for (int t4 = 0; t4 < 4; ++t4) {
      int ar = wm + t4 * 16 + fr;
      int as = (kg ^ ((ar >> 1) & 3)) * 8;
      fah[t4] = *(const v8s*)&Ah[ar * 32 + as];
      fal[t4] = *(const v8s*)&Al[ar * 32 + as];
      int bc = wn + t4 * 16 + fr;
      int bs = (kg ^ ((bc >> 1) & 3)) * 8;
      fbh[t4] = *(const v8s*)&Bh[bc * 32 + bs];
      fbl[t4] = *(const v8s*)&Bl[bc * 32 + bs];
    }
#pragma unroll
    for (int tm = 0; tm < 4; ++tm)
#pragma unroll
      for (int tn = 0; tn < 4; ++tn) {
        acc[tm][tn] = __builtin_amdgcn_mfma_f32_16x16x32_bf16(fal[tm], fbh[tn], acc[tm][tn], 0, 0, 0);
        acc[tm][tn] = __builtin_amdgcn_mfma_f32_16x16x32_bf16(fah[tm], fbl[tn], acc[tm][tn], 0, 0, 0);
        acc[tm][tn] = __builtin_amdgcn_mfma_f32_16x16x32_bf16(fah[tm], fbh[tn], acc[tm][tn], 0, 0, 0);
      }
  }
  // ---- epilogue: D lane mapping col=l&15, row=(l>>4)*4+r
#pragma unroll
  for (int tm = 0; tm < 4; ++tm) {
    const int mb = m0 + wm + tm * 16 + kg * 4;
#pragma unroll
    for (int tn = 0; tn < 4; ++tn) {
      const int n = n0 + wn + tn * 16 + fr;
#pragma unroll
      for (int r = 0; r < 4; ++r) {
        float vv = acc[tm][tn][r];
        int m = mb + r;
        if (n < COLS_)       gout[(size_t)m * COLS_ + n] = vv;
        else if (n >= 1664)  yout[m * 128 + (n - 1664)] = vv;
        else if (n >= 1536)  uout[m * 128 + (n - 1536)] = vv;
      }
    }
  }
}

extern "C" void kernel_launch(void* const* d_in, const int* in_sizes, int n_in,
                              void* d_out, int out_size, void* d_ws, size_t ws_size,
                              hipStream_t stream) {
  (void)in_sizes; (void)n_in; (void)out_size; (void)ws_size;
  const float* ref   = (const float*)d_in[0];
  const float* u_ini = (const float*)d_in[2];
  const float* y_ini = (const float*)d_in[3];
  const float* ud    = (const float*)d_in[4];
  const float* yd    = (const float*)d_in[5];
  const float* q     = (const float*)d_in[6];
  const float* r     = (const float*)d_in[7];

  float* out  = (float*)d_out;
  float* gout = out;
  float* uout = out + (size_t)NB * COLS_;
  float* yout = uout + (size_t)NB * 128;

  double* Wd  = (double*)d_out;
  double* Gam = Wd + oGam;
  double* c   = Wd + oC;
  double* v   = Wd + oV;
  double* GC  = Wd + oGC;
  double* cK  = Wd + oCK;
  double* vK  = Wd + oVK;
  double* GCK = Wd + oGCK;
  double* Ba  = Wd + oB;
  double* P   = Wd + oP;
  double* R   = Wd + oR;
  double* J   = Wd + oJ;
  double* F   = Wd + oF;
  double* CEt = Wd + oCE;
  unsigned short* Eh = (unsigned short*)d_ws;              // 256x1792 bf16 hi plane
  unsigned short* El = Eh + (size_t)256 * EGS;             // 256x1792 bf16 lo plane

  // 1) Gram matrix (the only 1453-deep f64 kernel)
  k_gram<<<dim3(24, 24), dim3(16, 16), 0, stream>>>(ud, yd, Gam);

  // 2) block power iteration for the dominant-128 subspace — FUSED k_G+k_step
  //    (GC never materialized inside the loop; bit-identical math)
  k_initc<<<dim3(8, 33), dim3(16, 16), 0, stream>>>(c, v);
  double* ca = c;  double* va = v;
  double* cb = cK; double* vb = vK;
  for (int it = 0; it < 4; ++it) {
    k_Gstep<<<dim3(8, 24), dim3(16, 16), 0, stream>>>(Gam, ca, va, q, r, cb, vb);
    double* t1 = ca; ca = cb; cb = t1;
    double* t2 = va; va = vb; vb = t2;
  }
  // ca/va hold the iterate (== c/v buffers after 4 swaps)

  // 3) normalize; KZ in coordinates; B = Z^T K Z
  k_G<<<dim3(8, 24), dim3(16, 16), 0, stream>>>(Gam, ca, GC);
  k_normc<<<128, 256, 0, stream>>>(ca, va, GC);
  k_step<<<dim3(8, 33), dim3(16, 16), 0, stream>>>(GC, va, q, r, cb, vb);
  k_G<<<dim3(8, 24), dim3(16, 16), 0, stream>>>(Gam, cb, GCK);
  k_B<<<dim3(16, 8), dim3(16, 16), 0, stream>>>(ca, GCK, va, vb, Ba);

  // 4) invert B (128x128 SPD), 2-step blocked GJ (R2/R5-proven a[8] kernel)
  for (int k = 0; k < 2; ++k) {
    k_inv<<<1, 512, 0, stream>>>(Ba + (size_t)(64 * k) * 256 + 64 * k, 256, P, 64);
    int cs = 64 * (k + 1);
    int gx = (256 - cs + 63) / 64;
    k_rowscale<<<dim3(gx, 64), 64, 0, stream>>>(Ba, P, R, 256, 64, k);
    k_update<<<dim3(gx, 128), 64, 0, stream>>>(Ba, R, 256, 64, 64, k);
  }

  // 5) input->coefficient map and the three output maps (bf16 hi/lo planes)
  k_J<<<dim3(16, 8), dim3(16, 16), 0, stream>>>(GC, va, q, J);
  k_F<<<dim3(16, 8), dim3(16, 16), 0, stream>>>(Ba, J, F);
  k_CE<<<dim3(24, 16), dim3(16, 16), 0, stream>>>(ca, F, CEt);
  k_Egt<<<dim3(96, 16), dim3(16, 16), 0, stream>>>(CEt, ud, yd, Eh, El);
  k_Euy<<<dim3(16, 16), dim3(16, 16), 0, stream>>>(GC, F, Eh, El);

  // 6) one batch MFMA GEMM produces g, u, y
  k_gemm1<<<dim3(14, 64), dim3(256), 0, stream>>>(ref, u_ini, y_ini, Eh, El, gout, uout, yout);
}